// Round 7
// baseline (142.890 us; speedup 1.0000x reference)
//
#include <hip/hip_runtime.h>
#include <math.h>

#define NB 32    // batch
#define NS 128   // steps
#define NI 256   // in_dim
#define NC 128   // num capsules
#define ND 64    // dim capsule
#define PAD 68   // pe2 tile row stride (floats)

#define L4 9.210340371976184f  // ln(10000)

// ---------------------------------------------------------------------------
// k_prep:
//   blocks [0,1024):      M[b,s,d] = sum_i u*W ; U[b,s] = sum_i u
//   blocks [1024,1056):   PE1[n][d]
// ---------------------------------------------------------------------------
__global__ __launch_bounds__(256) void k_prep(const float* __restrict__ u,
                                              const float* __restrict__ W,
                                              float* __restrict__ M,
                                              float* __restrict__ U,
                                              float* __restrict__ PE1) {
    int blk = blockIdx.x;
    int t = threadIdx.x;
    if (blk < 1024) {
        int row = blk * 4 + (t >> 6);   // b*NS + s
        int d = t & 63;
        const float* ur = u + row * NI;
        float acc = 0.f, rs = 0.f;
#pragma unroll 4
        for (int i = 0; i < NI; ++i) {
            float v = ur[i];
            acc = fmaf(v, W[i * ND + d], acc);
            rs += v;
        }
        M[row * ND + d] = acc;
        if (d == 0) U[row] = rs;
    } else {
        int idx = (blk - 1024) * 256 + t;   // 8192 elems, [n][d]
        int n = idx >> 6, d = idx & 63;
        float ang = (float)n * __expf(-L4 * (float)(d >> 1) * (1.f / 32.f));
        float sv, cv;
        __sincosf(ang, &sv, &cv);
        PE1[idx] = (d & 1) ? cv : sv;
    }
}

// ---------------------------------------------------------------------------
// kIter: one full routing iteration. Block = (n, 8-batch tile): 512 blocks,
// 512 threads, ~62.5 KB LDS -> exactly 2 blocks/CU co-resident (16 waves).
//   Phase A: pe2[s][d] tile for this n, built once (1 exp + 8 sincos/thread),
//            SHARED across the 8 b's (8x trig amortization vs per-(b,n) blocks)
//   Phase B: acc[bi] += c[bi,s]*(M[bi,s,dq]+pe2[s,dq]) over owned s (coalesced
//            1 KB/wave M loads); pe1*U folded as pe1*T2 (T2 = sum_s c*U).
//   Phase C: shfl + LDS reduce over s-partials; add pe1*T2; squash scale;
//            PUu = sum_d outp*pe1.
//   Phase D (if !last): bl[bi,n,s] = scale*(sum_d outp*(M+pe2) + PUu*U[bi,s]),
//            4 rounds of 16 KB LDS scratch; coalesced bl stores.
// ---------------------------------------------------------------------------
__global__ __launch_bounds__(512) void kIter(const float* __restrict__ M,
                                             const float* __restrict__ U,
                                             const float* __restrict__ PE1,
                                             const float* __restrict__ cg,
                                             const float* __restrict__ mask,
                                             float* __restrict__ og,
                                             float* __restrict__ bl,
                                             int first, int last) {
    int n  = blockIdx.x >> 2;
    int b0 = (blockIdx.x & 3) * 8;
    int t  = threadIdx.x;

    __shared__ float  pe2t[NS * PAD];    // 34816 B
    __shared__ float  cs[8][NS];         // 4096
    __shared__ float  Ut[8][NS];         // 4096
    __shared__ float4 redw[8][8][16];    // 16384 (reused as red2[32][8][16] floats)
    __shared__ float4 outs[8][16];       // 2048
    __shared__ float  ssp[8][16];        // 512
    __shared__ float  ppu[8][16];        // 512
    __shared__ float  T2[8], scal[8], PUu[8];

    // ---- stage c, U ----
#pragma unroll
    for (int k = 0; k < 2; ++k) {
        int idx = k * 512 + t;
        int bi = idx >> 7, s = idx & 127;
        Ut[bi][s] = U[(b0 + bi) * NS + s];
        cs[bi][s] = first ? mask[(b0 + bi) * NS + s] * (1.f / 128.f)
                          : cg[((b0 + bi) * NC + n) * NS + s];
    }

    // ---- phase A: pe2 tile (freq fixed per thread: kk = t&31) ----
    {
        int kk = t & 31;
        float g = __expf(-L4 * (float)(n * 32 + kk) * (1.f / 4096.f));
        int sbase = t >> 5;              // 0..15
#pragma unroll
        for (int k = 0; k < 8; ++k) {
            int s = k * 16 + sbase;
            float sv, cv;
            __sincosf((float)s * g, &sv, &cv);
            *(float2*)&pe2t[s * PAD + 2 * kk] = make_float2(sv, cv);
        }
    }
    __syncthreads();

    int dq = t & 15, sq = t >> 4;
    const float4* M4 = (const float4*)M;

    // ---- phase B: T-partials over owned s ----
    float4 acc[8];
#pragma unroll
    for (int bi = 0; bi < 8; ++bi) acc[bi] = make_float4(0.f, 0.f, 0.f, 0.f);
#pragma unroll
    for (int k = 0; k < 4; ++k) {
        int s = k * 32 + sq;
        float4 p2 = *(const float4*)&pe2t[s * PAD + 4 * dq];
#pragma unroll
        for (int bi = 0; bi < 8; ++bi) {
            float4 m = M4[((b0 + bi) * NS + s) * 16 + dq];
            float cc = cs[bi][s];
            acc[bi].x = fmaf(cc, m.x + p2.x, acc[bi].x);
            acc[bi].y = fmaf(cc, m.y + p2.y, acc[bi].y);
            acc[bi].z = fmaf(cc, m.z + p2.z, acc[bi].z);
            acc[bi].w = fmaf(cc, m.w + p2.w, acc[bi].w);
        }
    }
    // in-wave reduce over the 4 sq values sharing a wave (xor 16, 32)
#pragma unroll
    for (int bi = 0; bi < 8; ++bi) {
#pragma unroll
        for (int o = 16; o <= 32; o <<= 1) {
            acc[bi].x += __shfl_xor(acc[bi].x, o);
            acc[bi].y += __shfl_xor(acc[bi].y, o);
            acc[bi].z += __shfl_xor(acc[bi].z, o);
            acc[bi].w += __shfl_xor(acc[bi].w, o);
        }
    }
    if ((t & 48) == 0) {
        int w = t >> 6;
#pragma unroll
        for (int bi = 0; bi < 8; ++bi) redw[w][bi][dq] = acc[bi];
    }
    __syncthreads();

    // ---- phase C: combine, squash ----
    float4 p14 = ((const float4*)PE1)[n * 16 + dq];
    if (t < 128) {
        int bi = t >> 4, q = t & 15;
        float4 o = make_float4(0.f, 0.f, 0.f, 0.f);
#pragma unroll
        for (int w = 0; w < 8; ++w) {
            float4 r = redw[w][bi][q];
            o.x += r.x; o.y += r.y; o.z += r.z; o.w += r.w;
        }
        outs[bi][q] = o;
    }
    if (t < 8) {
        float s2 = 0.f;
        const float4* c4 = (const float4*)cs[t];
        const float4* u4 = (const float4*)Ut[t];
#pragma unroll
        for (int i = 0; i < 32; ++i) {
            float4 a = c4[i], b2 = u4[i];
            s2 += a.x * b2.x + a.y * b2.y + a.z * b2.z + a.w * b2.w;
        }
        T2[t] = s2;
    }
    __syncthreads();
    if (t < 128) {
        int bi = t >> 4, q = t & 15;
        float4 o = outs[bi][q];
        float t2 = T2[bi];
        o.x = fmaf(p14.x, t2, o.x);
        o.y = fmaf(p14.y, t2, o.y);
        o.z = fmaf(p14.z, t2, o.z);
        o.w = fmaf(p14.w, t2, o.w);
        outs[bi][q] = o;
        ssp[bi][q] = o.x * o.x + o.y * o.y + o.z * o.z + o.w * o.w;
        ppu[bi][q] = o.x * p14.x + o.y * p14.y + o.z * p14.z + o.w * p14.w;
    }
    __syncthreads();
    if (t < 8) {
        float ss = 0.f, pp = 0.f;
#pragma unroll
        for (int q = 0; q < 16; ++q) { ss += ssp[t][q]; pp += ppu[t][q]; }
        scal[t] = ss / (1.f + ss) * rsqrtf(ss + 1e-7f);
        PUu[t] = pp;
    }
    __syncthreads();

    if (last) {
        if (t < 128) {
            int bi = t >> 4, q = t & 15;
            float sc = scal[bi];
            float4 o = outs[bi][q];
            o.x *= sc; o.y *= sc; o.z *= sc; o.w *= sc;
            ((float4*)og)[((b0 + bi) * NC + n) * 16 + q] = o;
        }
        return;
    }

    // ---- phase D: logits ----
    float* red2 = (float*)redw;          // [sq2][bi][dq] = [32][8][16]
#pragma unroll
    for (int k = 0; k < 4; ++k) {
        int s = k * 32 + sq;
        float4 p2 = *(const float4*)&pe2t[s * PAD + 4 * dq];
#pragma unroll
        for (int bi = 0; bi < 8; ++bi) {
            float4 m = M4[((b0 + bi) * NS + s) * 16 + dq];
            float4 o = outs[bi][dq];
            red2[(sq * 8 + bi) * 16 + dq] =
                (m.x + p2.x) * o.x + (m.y + p2.y) * o.y +
                (m.z + p2.z) * o.z + (m.w + p2.w) * o.w;
        }
        __syncthreads();
        if (t < 256) {
            int bi = t >> 5, sq2 = t & 31;
            int s2 = k * 32 + sq2;
            const float4* r = (const float4*)&red2[(sq2 * 8 + bi) * 16];
            float4 a = r[0], b2 = r[1], c2 = r[2], d2 = r[3];
            float sum = a.x + a.y + a.z + a.w + b2.x + b2.y + b2.z + b2.w
                      + c2.x + c2.y + c2.z + c2.w + d2.x + d2.y + d2.z + d2.w;
            bl[((b0 + bi) * NC + n) * NS + s2] =
                scal[bi] * (sum + Ut[bi][s2] * PUu[bi]);
        }
        __syncthreads();
    }
}

// ---------------------------------------------------------------------------
// kS: softmax over n for each (b,s); c[b,n,s] = softmax_n(bl[b,n,s])*mask.
// bl/c layout [b][n][s]. Block = (b, 16-s tile), 256 thr. grid = 256.
// ---------------------------------------------------------------------------
__global__ __launch_bounds__(256) void kS(const float* __restrict__ bl,
                                          const float* __restrict__ mask,
                                          float* __restrict__ c) {
    int blk = blockIdx.x;
    int b = blk >> 3, s0 = (blk & 7) * 16;
    int t = threadIdx.x;

    __shared__ float tl[NC][17];
    __shared__ float pr[16][17];
    __shared__ float ps[16][17];
    __shared__ float itot[16], msk[16];

    if (t < 16) msk[t] = mask[b * NS + s0 + t];
#pragma unroll
    for (int i = 0; i < 8; ++i) {
        int idx = i * 256 + t;
        int n = idx >> 4, si = idx & 15;
        tl[n][si] = bl[(b * NC + n) * NS + s0 + si];
    }
    __syncthreads();

    int si = t & 15, ch = t >> 4;      // 16 chunks x 8 n each
    float mx = -1e30f;
#pragma unroll
    for (int j = 0; j < 8; ++j) mx = fmaxf(mx, tl[ch * 8 + j][si]);
    pr[ch][si] = mx;
    __syncthreads();

    mx = pr[0][si];
#pragma unroll
    for (int jc = 1; jc < 16; ++jc) mx = fmaxf(mx, pr[jc][si]);
    float sm = 0.f;
#pragma unroll
    for (int j = 0; j < 8; ++j) {
        float e = __expf(tl[ch * 8 + j][si] - mx);
        tl[ch * 8 + j][si] = e;       // owner-exclusive rows: no race
        sm += e;
    }
    ps[ch][si] = sm;
    __syncthreads();

    if (t < 16) {
        float tot = 0.f;
#pragma unroll
        for (int jc = 0; jc < 16; ++jc) tot += ps[jc][t];
        itot[t] = msk[t] / tot;
    }
    __syncthreads();

#pragma unroll
    for (int i = 0; i < 8; ++i) {
        int idx = i * 256 + t;
        int n = idx >> 4, sj = idx & 15;
        c[(b * NC + n) * NS + s0 + sj] = tl[n][sj] * itot[sj];
    }
}

// ---------------------------------------------------------------------------
extern "C" void kernel_launch(void* const* d_in, const int* in_sizes, int n_in,
                              void* d_out, int out_size, void* d_ws, size_t ws_size,
                              hipStream_t stream) {
    const float* u    = (const float*)d_in[0];  // (32,128,256)
    const float* mask = (const float*)d_in[1];  // (32,128)
    const float* W    = (const float*)d_in[2];  // (1,256,64)
    float* out = (float*)d_out;                 // (32,128,64) = [b][n][d]

    float* ws  = (float*)d_ws;
    float* M   = ws;                            // 262144
    float* U   = M + NB * NS * ND;              // 4096
    float* PE1 = U + NB * NS;                   // 8192
    float* c   = PE1 + NC * ND;                 // 524288  [b][n][s]
    float* bl  = c + NB * NC * NS;              // 524288  [b][n][s]

    k_prep<<<1056, 256, 0, stream>>>(u, W, M, U, PE1);

    // iter 0 (uniform c = mask/128) -> logits bl
    kIter<<<512, 512, 0, stream>>>(M, U, PE1, c, mask, out, bl, 1, 0);
    kS<<<NB * 8, 256, 0, stream>>>(bl, mask, c);
    // iter 1 -> logits bl
    kIter<<<512, 512, 0, stream>>>(M, U, PE1, c, mask, out, bl, 0, 0);
    kS<<<NB * 8, 256, 0, stream>>>(bl, mask, c);
    // iter 2 (final) -> d_out
    kIter<<<512, 512, 0, stream>>>(M, U, PE1, c, mask, out, bl, 0, 1);
}

// Round 8
// 114.835 us; speedup vs baseline: 1.2443x; 1.2443x over previous
//
#include <hip/hip_runtime.h>
#include <math.h>

#define NB 32    // batch
#define NS 128   // steps
#define NI 256   // in_dim
#define NC 128   // num capsules
#define ND 64    // dim capsule

#define L4 9.210340371976184f  // ln(10000)

// ---------------------------------------------------------------------------
// k_prep:
//   blocks [0,1024):      M[b,s,d] = sum_i u*W ; U[b,s] = sum_i u
//   blocks [1024,1056):   PE1[n][d]
// ---------------------------------------------------------------------------
__global__ __launch_bounds__(256) void k_prep(const float* __restrict__ u,
                                              const float* __restrict__ W,
                                              float* __restrict__ M,
                                              float* __restrict__ U,
                                              float* __restrict__ PE1) {
    int blk = blockIdx.x;
    int t = threadIdx.x;
    if (blk < 1024) {
        int row = blk * 4 + (t >> 6);   // b*NS + s
        int d = t & 63;
        const float* ur = u + row * NI;
        float acc = 0.f, rs = 0.f;
#pragma unroll 4
        for (int i = 0; i < NI; ++i) {
            float v = ur[i];
            acc = fmaf(v, W[i * ND + d], acc);
            rs += v;
        }
        M[row * ND + d] = acc;
        if (d == 0) U[row] = rs;
    } else {
        int idx = (blk - 1024) * 256 + t;   // 8192 elems, [n][d]
        int n = idx >> 6, d = idx & 63;
        float ang = (float)n * __expf(-L4 * (float)(d >> 1) * (1.f / 32.f));
        float sv, cv;
        __sincosf(ang, &sv, &cv);
        PE1[idx] = (d & 1) ? cv : sv;
    }
}

// ---------------------------------------------------------------------------
// kR v4: one routing iteration, one block per (b,n). 256 threads, ~10.3 KB
// LDS -> ~6-8 blocks/CU (24-32 waves). Thread (sq=t>>4, dq=t&15) owns
// s in [sq*8, sq*8+8) x d-quad dq -> 32 u-hat elems in registers.
//   staging: cs[s] to LDS; T2 = sum_s c*U via wave shfl (pe1*U folded out
//            of the build algebraically: out_pre = sum c*(M+pe2) + pe1*T2).
//   pass 1: v = M4 + pe2(in-register sincos); acc += c[s]*v. shfl-reduce
//           over the 4 sq-chunks in each wave, LDS-combine 4 waves, then
//           16-thread tail adds pe1*T2, squash scale, PUu = sum outp*pe1.
//   pass 2: per owned s: dot(v, outs4[dq]) -> red2[s*17+dq] (2-way banks,
//           free); 128 threads sum 16 partials (stride-17: conflict-free)
//           + PUu*U[s]; coalesced bl store.
// grid = 4096. Global traffic: M once (134 MB/launch, L2-resident).
// ---------------------------------------------------------------------------
__global__ __launch_bounds__(256) void kR(const float* __restrict__ M,
                                          const float* __restrict__ U,
                                          const float* __restrict__ PE1,
                                          const float* __restrict__ cg,
                                          const float* __restrict__ mask,
                                          float* __restrict__ og,
                                          float* __restrict__ bl,
                                          int first, int last) {
    int bn = blockIdx.x;
    int b = bn >> 7, n = bn & 127;
    int t = threadIdx.x;

    __shared__ float  cs[NS];           //  512 B
    __shared__ float4 redw[4][16];      // 1024 B
    __shared__ float4 outs4[16];        //  256 B
    __shared__ float  tpar[2];          // T2 wave-partials
    __shared__ float  sc2[2];           // {scale, PUu}
    __shared__ float  red2[NS * 17];    // 8704 B

    // ---- staging: c, and T2 = sum_s c*U (wave-level reduce, waves 0-1) ----
    if (t < NS) {
        float cv = first ? mask[b * NS + t] * (1.f / 128.f) : cg[bn * NS + t];
        cs[t] = cv;
        float p = cv * U[b * NS + t];
#pragma unroll
        for (int o = 32; o > 0; o >>= 1) p += __shfl_xor(p, o);
        if ((t & 63) == 0) tpar[t >> 6] = p;
    }

    int dq = t & 15, sq = t >> 4;
    int s0 = sq * 8;
    // pe2 frequencies for this (n, d-quad): two pairs (sin,cos share angle)
    int k2 = n * 32 + dq * 2;
    float g0 = __expf(-L4 * (float)k2 * (1.f / 4096.f));
    float g1 = __expf(-L4 * (float)(k2 + 1) * (1.f / 4096.f));
    __syncthreads();

    // ---- pass 1: build v = M + pe2 (registers), acc += c*v ----
    const float4* M4 = (const float4*)(M + (size_t)(b * NS) * ND) + dq;
    float4 v[8];
    float4 acc = make_float4(0.f, 0.f, 0.f, 0.f);
#pragma unroll
    for (int i = 0; i < 8; ++i) {
        int s = s0 + i;
        float4 m4 = M4[s * 16];
        float sf = (float)s;
        float sa, ca, sb, cb;
        __sincosf(sf * g0, &sa, &ca);
        __sincosf(sf * g1, &sb, &cb);
        float4 vv;
        vv.x = m4.x + sa; vv.y = m4.y + ca;
        vv.z = m4.z + sb; vv.w = m4.w + cb;
        v[i] = vv;
        float cc = cs[s];
        acc.x = fmaf(cc, vv.x, acc.x);
        acc.y = fmaf(cc, vv.y, acc.y);
        acc.z = fmaf(cc, vv.z, acc.z);
        acc.w = fmaf(cc, vv.w, acc.w);
    }
    // reduce the 4 sq-chunks within each wave (lanes xor 16, 32)
#pragma unroll
    for (int o = 16; o <= 32; o <<= 1) {
        acc.x += __shfl_xor(acc.x, o);
        acc.y += __shfl_xor(acc.y, o);
        acc.z += __shfl_xor(acc.z, o);
        acc.w += __shfl_xor(acc.w, o);
    }
    if ((t & 48) == 0) redw[t >> 6][dq] = acc;   // one writer per (wave, dq)
    __syncthreads();

    // ---- combine + squash (wave 0, lanes 0-15; shfl partners all active) --
    if (t < 16) {
        float4 r0 = redw[0][t], r1 = redw[1][t], r2 = redw[2][t], r3 = redw[3][t];
        float4 o;
        o.x = r0.x + r1.x + r2.x + r3.x;
        o.y = r0.y + r1.y + r2.y + r3.y;
        o.z = r0.z + r1.z + r2.z + r3.z;
        o.w = r0.w + r1.w + r2.w + r3.w;
        float T2 = tpar[0] + tpar[1];
        float4 p14 = ((const float4*)PE1)[n * 16 + t];
        o.x = fmaf(p14.x, T2, o.x);
        o.y = fmaf(p14.y, T2, o.y);
        o.z = fmaf(p14.z, T2, o.z);
        o.w = fmaf(p14.w, T2, o.w);
        outs4[t] = o;                    // pre-squash out_pre
        float ssq = o.x * o.x + o.y * o.y + o.z * o.z + o.w * o.w;
        float ppu = o.x * p14.x + o.y * p14.y + o.z * p14.z + o.w * p14.w;
#pragma unroll
        for (int o2 = 1; o2 <= 8; o2 <<= 1) {
            ssq += __shfl_xor(ssq, o2);
            ppu += __shfl_xor(ppu, o2);
        }
        if (t == 0) {
            sc2[0] = ssq / (1.f + ssq) * rsqrtf(ssq + 1e-7f);
            sc2[1] = ppu;
        }
    }
    __syncthreads();
    float scale = sc2[0];

    if (last) {
        if (t < 16) {
            float4 o = outs4[t];
            o.x *= scale; o.y *= scale; o.z *= scale; o.w *= scale;
            ((float4*)og)[bn * 16 + t] = o;
        }
        return;
    }

    // ---- pass 2: bl[s] = scale*(sum_d outp*(M+pe2) + PUu*U[s]) ----
    float4 o4 = outs4[dq];
#pragma unroll
    for (int i = 0; i < 8; ++i) {
        int s = s0 + i;
        float4 vv = v[i];
        red2[s * 17 + dq] = vv.x * o4.x + vv.y * o4.y + vv.z * o4.z + vv.w * o4.w;
    }
    __syncthreads();
    if (t < NS) {
        const float* r = red2 + t * 17;
        float sum = 0.f;
#pragma unroll
        for (int q = 0; q < 16; ++q) sum += r[q];
        bl[bn * NS + t] = scale * (sum + sc2[1] * U[b * NS + t]);
    }
}

// ---------------------------------------------------------------------------
// kS: softmax over n for each (b,s); c[b,n,s] = softmax_n(bl[b,n,s])*mask.
// bl/c layout [b][n][s]. Block = (b, 16-s tile), 256 thr. grid = 256.
// ---------------------------------------------------------------------------
__global__ __launch_bounds__(256) void kS(const float* __restrict__ bl,
                                          const float* __restrict__ mask,
                                          float* __restrict__ c) {
    int blk = blockIdx.x;
    int b = blk >> 3, s0 = (blk & 7) * 16;
    int t = threadIdx.x;

    __shared__ float tl[NC][17];
    __shared__ float pr[16][17];
    __shared__ float ps[16][17];
    __shared__ float itot[16], msk[16];

    if (t < 16) msk[t] = mask[b * NS + s0 + t];
#pragma unroll
    for (int i = 0; i < 8; ++i) {
        int idx = i * 256 + t;
        int n = idx >> 4, si = idx & 15;
        tl[n][si] = bl[(b * NC + n) * NS + s0 + si];
    }
    __syncthreads();

    int si = t & 15, ch = t >> 4;      // 16 chunks x 8 n each
    float mx = -1e30f;
#pragma unroll
    for (int j = 0; j < 8; ++j) mx = fmaxf(mx, tl[ch * 8 + j][si]);
    pr[ch][si] = mx;
    __syncthreads();

    mx = pr[0][si];
#pragma unroll
    for (int jc = 1; jc < 16; ++jc) mx = fmaxf(mx, pr[jc][si]);
    float sm = 0.f;
#pragma unroll
    for (int j = 0; j < 8; ++j) {
        float e = __expf(tl[ch * 8 + j][si] - mx);
        tl[ch * 8 + j][si] = e;       // owner-exclusive rows: no race
        sm += e;
    }
    ps[ch][si] = sm;
    __syncthreads();

    if (t < 16) {
        float tot = 0.f;
#pragma unroll
        for (int jc = 0; jc < 16; ++jc) tot += ps[jc][t];
        itot[t] = msk[t] / tot;
    }
    __syncthreads();

#pragma unroll
    for (int i = 0; i < 8; ++i) {
        int idx = i * 256 + t;
        int n = idx >> 4, sj = idx & 15;
        c[(b * NC + n) * NS + s0 + sj] = tl[n][sj] * itot[sj];
    }
}

// ---------------------------------------------------------------------------
extern "C" void kernel_launch(void* const* d_in, const int* in_sizes, int n_in,
                              void* d_out, int out_size, void* d_ws, size_t ws_size,
                              hipStream_t stream) {
    const float* u    = (const float*)d_in[0];  // (32,128,256)
    const float* mask = (const float*)d_in[1];  // (32,128)
    const float* W    = (const float*)d_in[2];  // (1,256,64)
    float* out = (float*)d_out;                 // (32,128,64) = [b][n][d]

    float* ws  = (float*)d_ws;
    float* M   = ws;                            // 262144
    float* U   = M + NB * NS * ND;              // 4096
    float* PE1 = U + NB * NS;                   // 8192
    float* c   = PE1 + NC * ND;                 // 524288  [b][n][s]
    float* bl  = c + NB * NC * NS;              // 524288  [b][n][s]

    k_prep<<<1056, 256, 0, stream>>>(u, W, M, U, PE1);

    // iter 0 (uniform c = mask/128) -> logits bl
    kR<<<NB * NC, 256, 0, stream>>>(M, U, PE1, c, mask, out, bl, 1, 0);
    kS<<<NB * 8, 256, 0, stream>>>(bl, mask, c);
    // iter 1 -> logits bl
    kR<<<NB * NC, 256, 0, stream>>>(M, U, PE1, c, mask, out, bl, 0, 0);
    kS<<<NB * 8, 256, 0, stream>>>(bl, mask, c);
    // iter 2 (final) -> d_out
    kR<<<NB * NC, 256, 0, stream>>>(M, U, PE1, c, mask, out, bl, 0, 1);
}